// Round 12
// baseline (84.196 us; speedup 1.0000x reference)
//
#include <hip/hip_runtime.h>
#include <math.h>

namespace {
constexpr int kD = 512;
constexpr float kBetaMin = 0.1f;
constexpr float kBetaMax = 20.0f;
constexpr float kTMax = 1.0f;
// Spectrum of A = M M^T / D + I: lambda_min >= 1 (Wishart PSD),
// lambda_max ~ 4.96 (MP edge 4 + I + TW fluctuation). Containing bounds:
constexpr float kLamMin = 1.0f;
constexpr float kLamMax = 5.2f;
constexpr float kDelta = (kLamMax - kLamMin) * 0.5f;
constexpr int kSteps = 6;        // Chebyshev degree 7 -> 6 matvecs
                                 // (r12: was 7; truncation 2q^7 ~ 2.7e-3 rel,
                                 //  ~0.02 abs added -> still 2x under threshold)
constexpr int kGroupsC = 32;     // independent groups (16 batch-columns each)
constexpr int kMembers = 8;      // blocks per group (64 A-rows each)
constexpr int kCPG = 16;         // columns per group
constexpr int kRowsB = 64;       // A-rows per block (held in LDS)
constexpr int kBarStride = 32;   // unsigneds per counter -> 128 B line each
constexpr int kFragElems = kCPG * kD;   // 8192 bf16 = 16 KB per group D-block

typedef __attribute__((ext_vector_type(8))) short short8;   // 8 bf16
typedef __attribute__((ext_vector_type(4))) float float4v;  // 4 fp32 acc
}

__device__ inline unsigned short bf16_rne(float f) {
  unsigned u = __float_as_uint(f);
  u = (u + 0x7FFFu + ((u >> 16) & 1u)) >> 16;
  return (unsigned short)u;
}

// Coherence-bypassing 8 B accessors (relaxed agent-scope atomics ->
// global_{load,store}_dwordx2 sc0 sc1: through the non-coherent XCD L2 to the
// Infinity Cache; no buffer_wbl2/buffer_inv anywhere — r10/r11-proven).
__device__ inline void store8_agent(void* p, unsigned lo, unsigned hi) {
  const unsigned long long v = (unsigned long long)lo | ((unsigned long long)hi << 32);
  __hip_atomic_store((unsigned long long*)p, v, __ATOMIC_RELAXED,
                     __HIP_MEMORY_SCOPE_AGENT);
}
__device__ inline unsigned long long load8_agent(const void* p) {
  return __hip_atomic_load((const unsigned long long*)p, __ATOMIC_RELAXED,
                           __HIP_MEMORY_SCOPE_AGENT);
}

// ---------------- Fused persistent-chain path (batch == 512) ----------------
// 256 blocks = 32 groups x 8 members. Group g owns batch columns [16g,16g+16);
// member m owns A rows [64m,64m+64) (bf16 in LDS, MFMA-fragment order).
// Dt in global is PER-GROUP FRAGMENT-ORDERED (16 KB contiguous per group).
// r12 vs r11: B-fragments are loaded DIRECTLY to registers after the barrier
// (32 x 8 B coalesced sc0sc1 loads, one latency exposure, compiler pipelines
// the vmcnt waits into the MFMA chain) — removes the per-step LDS write +
// second __syncthreads + ds_read from the critical path. Steps 7 -> 6.
__global__ __launch_bounds__(256) void cheb_fused(
    const float* __restrict__ x,    // [B, D]
    const float* __restrict__ t,    // [B]
    const float* __restrict__ mu,   // [D]
    const float* __restrict__ A,    // [D, D] fp32
    float* __restrict__ out,        // [B, D]
    unsigned short* __restrict__ Dt0,   // fragment-ordered ping (32 x 16 KB)
    unsigned short* __restrict__ Dt1,   // fragment-ordered pong
    unsigned* __restrict__ bars) {      // [32*kBarStride] zeroed counters
  const int group = blockIdx.x & (kGroupsC - 1);
  const int member = blockIdx.x >> 5;
  const int c0 = group * kCPG;
  const int i0 = member * kRowsB;
  const int tid = threadIdx.x;
  const int wave = tid >> 6;
  const int lane = tid & 63;
  const int quad = lane >> 4;
  const int lc = lane & 15;
  const int c = c0 + lc;                    // this thread's batch column
  const int ibase = i0 + wave * 16 + quad * 4;  // 4 consecutive k (=row) indices

  // Producer fragment address: slot = (k>>5)*64 + ((k>>3)&3)*16 + col,
  // elem = slot*8 + (k&7). Thread's k=ibase..ibase+3 -> one aligned 8 B piece.
  const size_t fragOff = (size_t)group * kFragElems +
      (size_t)(((ibase >> 5) * 64 + ((ibase >> 3) & 3) * 16 + lc) * 8 + (ibase & 7));

  // LDS: A slab only (64 KB, fragment-ordered) -> 2 blocks/CU.
  __shared__ unsigned short As[kRowsB * kD];

  // --- per-column Chebyshev scalars (registers) ---
  const float tb = t[c];
  const float Bt = (kBetaMax - kBetaMin) / (2.0f * kTMax) * tb * tb + kBetaMin * tb;
  const float s_c = expm1f(Bt);
  const float eh = expf(0.5f * Bt);
  const float oscale = -eh * sqrtf(1.0f - expf(-Bt));
  const float theta = 0.5f * (kLamMin + kLamMax) + s_c;
  const float two_sig1 = 2.0f * theta / kDelta;
  const float c2base = 2.0f / kDelta;
  float rho_prev = kDelta / theta;          // 1/sigma1

  // --- state init + EARLY publish of D_1 (fragment-ordered 8 B store) ---
  float R[4], Dv[4], Y[4];
  {
    const float inv_theta = 1.0f / theta;
#pragma unroll
    for (int m = 0; m < 4; ++m) {
      const int i = ibase + m;
      const float b = eh * x[(size_t)c * kD + i] - mu[i];
      R[m] = b;
      Dv[m] = b * inv_theta;
      Y[m] = Dv[m];
    }
    store8_agent(Dt0 + fragOff,
                 (unsigned)bf16_rne(Dv[0]) | ((unsigned)bf16_rne(Dv[1]) << 16),
                 (unsigned)bf16_rne(Dv[2]) | ((unsigned)bf16_rne(Dv[3]) << 16));
  }

  // --- stage A slab fp32 -> bf16 (coalesced float4 reads) ---
  for (int idx = tid; idx < kRowsB * (kD / 4); idx += 256) {
    const int row = idx >> 7;
    const int col = (idx & 127) * 4;
    const float4 v = *(const float4*)(A + (size_t)(i0 + row) * kD + col);
    const int w = row >> 4, l = row & 15;
    const int kk = col >> 5, qd = (col >> 3) & 3, j = col & 7;
    uint2 wv;
    wv.x = (unsigned)bf16_rne(v.x) | ((unsigned)bf16_rne(v.y) << 16);
    wv.y = (unsigned)bf16_rne(v.z) | ((unsigned)bf16_rne(v.w) << 16);
    *(uint2*)&As[(w * 1024 + kk * 64 + qd * 16 + l) * 8 + j] = wv;
  }

  unsigned* ctr = bars + group * kBarStride;   // own 128 B line per group
  const unsigned short* groupIn0 = Dt0 + (size_t)group * kFragElems;
  const unsigned short* groupIn1 = Dt1 + (size_t)group * kFragElems;

  for (int k = 1; k <= kSteps; ++k) {
    // ---- 8-block group barrier (vmcnt drained by __syncthreads) ----
    __syncthreads();
    if (tid == 0) {
      __hip_atomic_fetch_add(ctr, 1u, __ATOMIC_RELAXED, __HIP_MEMORY_SCOPE_AGENT);
      const unsigned tgt = (unsigned)(kMembers * k);
      while (__hip_atomic_load(ctr, __ATOMIC_RELAXED, __HIP_MEMORY_SCOPE_AGENT) < tgt)
        __builtin_amdgcn_s_sleep(2);
    }
    __syncthreads();

    // ---- B-fragments DIRECT to registers: 32 coalesced 8 B sc0sc1 loads.
    // Fragment order => lane's chunk kk lives at contiguous 16 B
    // (kk*64+lane)*16; consecutive lanes -> consecutive 16 B segments.
    const unsigned short* gin = (k & 1) ? groupIn0 : groupIn1;
    unsigned long long blo[kD / 32], bhi[kD / 32];
#pragma unroll
    for (int kk = 0; kk < kD / 32; ++kk) {
      const char* p = (const char*)gin + ((size_t)(kk * 64 + lane) * 16);
      blo[kk] = load8_agent(p);
      bhi[kk] = load8_agent(p + 8);
    }

    // ---- V-tile = A_slab x D (K = 512) ----
    float4v acc = {0.f, 0.f, 0.f, 0.f};
    const unsigned short* afp = As + (size_t)(wave * 1024 + lane) * 8;
#pragma unroll
    for (int kk = 0; kk < kD / 32; ++kk) {
      const short8 af = *(const short8*)(afp + (size_t)kk * 64 * 8);
      short8 bf;
      ((unsigned long long*)&bf)[0] = blo[kk];
      ((unsigned long long*)&bf)[1] = bhi[kk];
      acc = __builtin_amdgcn_mfma_f32_16x16x32_bf16(af, bf, acc, 0, 0, 0);
    }

    // ---- Chebyshev recurrence (exact fp32 diagonal term s_c * D) ----
    const float rho_new = 1.0f / (two_sig1 - rho_prev);
    const float cc1 = rho_new * rho_prev;
    const float cc2 = rho_new * c2base;
#pragma unroll
    for (int m = 0; m < 4; ++m) {
      const float v = acc[m] + s_c * Dv[m];
      R[m] -= v;
      Dv[m] = fmaf(cc1, Dv[m], cc2 * R[m]);
      Y[m] += Dv[m];
    }
    rho_prev = rho_new;

    if (k < kSteps) {
      unsigned short* gout = ((k & 1) ? Dt1 : Dt0);
      store8_agent(gout + fragOff,
                   (unsigned)bf16_rne(Dv[0]) | ((unsigned)bf16_rne(Dv[1]) << 16),
                   (unsigned)bf16_rne(Dv[2]) | ((unsigned)bf16_rne(Dv[3]) << 16));
    } else {
      float4 o;
      o.x = oscale * Y[0];
      o.y = oscale * Y[1];
      o.z = oscale * Y[2];
      o.w = oscale * Y[3];
      *(float4*)(out + (size_t)c * kD + ibase) = o;
    }
  }
}

// ---------------- Fallback path (r6 kernel, any batch) ----------------
__device__ inline unsigned pack_bf16_rne2(float a, float b) {
  unsigned ua = __float_as_uint(a), ub = __float_as_uint(b);
  ua = (ua + 0x7FFFu + ((ua >> 16) & 1u)) >> 16;
  ub = (ub + 0x7FFFu + ((ub >> 16) & 1u)) >> 16;
  return ua | (ub << 16);
}

__global__ __launch_bounds__(256) void a_to_bf16(
    const float* __restrict__ A, unsigned* __restrict__ Abf) {
  const int i = blockIdx.x * 256 + threadIdx.x;
  const float4 f = ((const float4*)A)[i];
  uint2 u;
  u.x = pack_bf16_rne2(f.x, f.y);
  u.y = pack_bf16_rne2(f.z, f.w);
  ((uint2*)Abf)[i] = u;
}

namespace {
constexpr int fGroups = 8;
constexpr int fTPG = 128;
constexpr int fThreads = fGroups * fTPG;
constexpr int fRowsG = kD / fGroups;
constexpr int fG = 2;
constexpr int fDeg = 8;
constexpr int fRows = 8;
}

__global__ __launch_bounds__(fThreads) void vp_sde_cheb_fb(
    const float* __restrict__ x, const float* __restrict__ t,
    const float* __restrict__ mu, const uint2* __restrict__ Abf,
    float* __restrict__ out, int batch) {
  const int b0 = blockIdx.x * fG;
  const int tid = threadIdx.x;
  const int grp = tid >> 7;
  const int tl = tid & (fTPG - 1);
  const int d0 = 4 * tl;
  const int jbase = grp * fRowsG;

  __shared__ alignas(16) float d_sh[fG][kD];
  __shared__ alignas(16) float red_sh[fGroups - 1][fG][kD];

  float s[fG], two_sig1[fG], rho_prev[fG], oscale[fG];
  bool vld[fG];
  float4 y[fG], r[fG], dv[fG];
  const float two_over_delta = 2.0f / kDelta;

  uint2 buf0[fRows], buf1[fRows];
#pragma unroll
  for (int rr = 0; rr < fRows; ++rr)
    buf0[rr] = Abf[(size_t)(jbase + rr) * (kD / 4) + tl];

#pragma unroll
  for (int g = 0; g < fG; ++g) {
    const int b = b0 + g;
    vld[g] = (b < batch);
    const float tb = vld[g] ? t[b] : 1.0f;
    const float Bt = (kBetaMin - kBetaMax) / (-2.0f * kTMax) * tb * tb + kBetaMin * tb;
    const float sg = expm1f(Bt);
    const float eh = expf(0.5f * Bt);
    s[g] = sg;
    oscale[g] = -eh * sqrtf(1.0f - expf(-Bt));
    const float theta = 0.5f * (kLamMin + kLamMax) + sg;
    const float sig1 = theta / kDelta;
    two_sig1[g] = 2.0f * sig1;
    rho_prev[g] = 1.0f / sig1;

    if (grp == 0) {
      float4 rv = {0.f, 0.f, 0.f, 0.f};
      if (vld[g]) {
        const float4 xv = *(const float4*)&x[(size_t)b * kD + d0];
        const float4 mu4 = *(const float4*)&mu[d0];
        rv.x = eh * xv.x - mu4.x;
        rv.y = eh * xv.y - mu4.y;
        rv.z = eh * xv.z - mu4.z;
        rv.w = eh * xv.w - mu4.w;
      }
      r[g] = rv;
      const float it = 1.0f / theta;
      dv[g].x = rv.x * it; dv[g].y = rv.y * it;
      dv[g].z = rv.z * it; dv[g].w = rv.w * it;
      y[g] = dv[g];
      *(float4*)&d_sh[g][d0] = dv[g];
    }
  }
  __syncthreads();

  for (int k = 1; k < fDeg; ++k) {
    float4 acc[fG];
#pragma unroll
    for (int g = 0; g < fG; ++g) acc[g] = {0.f, 0.f, 0.f, 0.f};

    auto stage = [&](uint2 (&cons)[fRows], uint2 (&ld)[fRows], int jc, int jl) {
#pragma unroll
      for (int rr = 0; rr < fRows; ++rr)
        ld[rr] = Abf[(size_t)(jbase + ((jl + rr) & (fRowsG - 1))) * (kD / 4) + tl];
      float4 pv[fG][fRows / 4];
#pragma unroll
      for (int g = 0; g < fG; ++g)
#pragma unroll
        for (int q = 0; q < fRows / 4; ++q)
          pv[g][q] = *(const float4*)&d_sh[g][jbase + jc + 4 * q];
#pragma unroll
      for (int q = 0; q < fRows / 4; ++q)
#pragma unroll
        for (int cc = 0; cc < 4; ++cc) {
          const uint2 u = cons[4 * q + cc];
          const float fa = __uint_as_float(u.x << 16);
          const float fb = __uint_as_float(u.x & 0xFFFF0000u);
          const float fc = __uint_as_float(u.y << 16);
          const float fd = __uint_as_float(u.y & 0xFFFF0000u);
#pragma unroll
          for (int g = 0; g < fG; ++g) {
            const float pj = (cc == 0) ? pv[g][q].x
                           : (cc == 1) ? pv[g][q].y
                           : (cc == 2) ? pv[g][q].z
                                       : pv[g][q].w;
            acc[g].x = fmaf(fa, pj, acc[g].x);
            acc[g].y = fmaf(fb, pj, acc[g].y);
            acc[g].z = fmaf(fc, pj, acc[g].z);
            acc[g].w = fmaf(fd, pj, acc[g].w);
          }
        }
    };

    int j = 0;
#pragma unroll 1
    for (int i = 0; i < fRowsG / (2 * fRows); ++i, j += 2 * fRows) {
      stage(buf0, buf1, j, j + fRows);
      stage(buf1, buf0, j + fRows, j + 2 * fRows);
    }

    if (grp != 0) {
#pragma unroll
      for (int g = 0; g < fG; ++g)
        *(float4*)&red_sh[grp - 1][g][d0] = acc[g];
    }
    __syncthreads();

    if (grp == 0) {
#pragma unroll
      for (int g = 0; g < fG; ++g) {
        float4 v = acc[g];
#pragma unroll
        for (int q = 0; q < fGroups - 1; ++q) {
          const float4 p = *(const float4*)&red_sh[q][g][d0];
          v.x += p.x; v.y += p.y; v.z += p.z; v.w += p.w;
        }
        v.x = fmaf(s[g], dv[g].x, v.x);
        v.y = fmaf(s[g], dv[g].y, v.y);
        v.z = fmaf(s[g], dv[g].z, v.z);
        v.w = fmaf(s[g], dv[g].w, v.w);
        r[g].x -= v.x; r[g].y -= v.y; r[g].z -= v.z; r[g].w -= v.w;
        const float rho = 1.0f / (two_sig1[g] - rho_prev[g]);
        const float c1 = rho * rho_prev[g];
        const float c2 = rho * two_over_delta;
        dv[g].x = fmaf(c1, dv[g].x, c2 * r[g].x);
        dv[g].y = fmaf(c1, dv[g].y, c2 * r[g].y);
        dv[g].z = fmaf(c1, dv[g].z, c2 * r[g].z);
        dv[g].w = fmaf(c1, dv[g].w, c2 * r[g].w);
        y[g].x += dv[g].x; y[g].y += dv[g].y;
        y[g].z += dv[g].z; y[g].w += dv[g].w;
        rho_prev[g] = rho;
        *(float4*)&d_sh[g][d0] = dv[g];
      }
    }
    __syncthreads();
  }

  if (grp == 0) {
#pragma unroll
    for (int g = 0; g < fG; ++g) {
      if (vld[g]) {
        float4 o;
        o.x = oscale[g] * y[g].x;
        o.y = oscale[g] * y[g].y;
        o.z = oscale[g] * y[g].z;
        o.w = oscale[g] * y[g].w;
        *(float4*)&out[(size_t)(b0 + g) * kD + d0] = o;
      }
    }
  }
}

extern "C" void kernel_launch(void* const* d_in, const int* in_sizes, int n_in,
                              void* d_out, int out_size, void* d_ws, size_t ws_size,
                              hipStream_t stream) {
  const float* x  = (const float*)d_in[0];   // [B, D] fp32
  const float* t  = (const float*)d_in[1];   // [B]    fp32
  const float* mu = (const float*)d_in[2];   // [D]    fp32
  const float* A  = (const float*)d_in[3];   // [D, D] fp32 SPD
  float* out = (float*)d_out;
  const int batch = in_sizes[1];

  char* ws = (char*)d_ws;
  const size_t barBytes = (size_t)kGroupsC * kBarStride * sizeof(unsigned);  // 4 KB
  const size_t need = 1024 * 1024 + barBytes;

  if (batch == kD && ws_size >= need) {
    unsigned short* Dt0 = (unsigned short*)(ws);                 // 512 KB
    unsigned short* Dt1 = (unsigned short*)(ws + 512 * 1024);    // 512 KB
    unsigned* bars = (unsigned*)(ws + 1024 * 1024);              // 4 KB

    hipMemsetAsync((void*)bars, 0, barBytes, stream);
    cheb_fused<<<kGroupsC * kMembers, 256, 0, stream>>>(
        x, t, mu, A, out, Dt0, Dt1, bars);
  } else {
    unsigned* Abf = (unsigned*)d_ws;
    a_to_bf16<<<(kD * kD / 4 + 255) / 256, 256, 0, stream>>>(A, Abf);
    const int blocks = (batch + fG - 1) / fG;
    vp_sde_cheb_fb<<<blocks, fThreads, 0, stream>>>(
        x, t, mu, (const uint2*)Abf, out, batch);
  }
}

// Round 13
// 79.109 us; speedup vs baseline: 1.0643x; 1.0643x over previous
//
#include <hip/hip_runtime.h>
#include <math.h>

namespace {
constexpr int kD = 512;
constexpr float kBetaMin = 0.1f;
constexpr float kBetaMax = 20.0f;
constexpr float kTMax = 1.0f;
// Spectrum of A = M M^T / D + I: lambda_min >= 1 (Wishart PSD),
// lambda_max ~ 4.96 (MP edge 4 + I + TW fluctuation). Containing bounds:
constexpr float kLamMin = 1.0f;
constexpr float kLamMax = 5.2f;
constexpr float kDelta = (kLamMax - kLamMin) * 0.5f;
// kSteps = matvec count (polynomial degree kSteps+1). Error ~ 2 q(s)^(k+1)
// scaled by eh*rescale, which vanishes where q is worst (s->0). Worst-case
// over s at k=5: ~0.03 abs + bf16 floor 0.016 -> ~0.045 vs threshold 0.089.
// Measured absmax stayed at the bf16 floor for k=7 AND k=6 (r11/r12).
constexpr int kSteps = 5;
constexpr int kGroupsC = 32;     // independent groups (16 batch-columns each)
constexpr int kMembers = 8;      // blocks per group (64 A-rows each)
constexpr int kCPG = 16;         // columns per group
constexpr int kRowsB = 64;       // A-rows per block (held in LDS)
constexpr int kBarStride = 32;   // unsigneds per counter -> 128 B line each
constexpr int kFragElems = kCPG * kD;   // 8192 bf16 = 16 KB per group D-block

typedef __attribute__((ext_vector_type(8))) short short8;   // 8 bf16
typedef __attribute__((ext_vector_type(4))) float float4v;  // 4 fp32 acc
}

__device__ inline unsigned short bf16_rne(float f) {
  unsigned u = __float_as_uint(f);
  u = (u + 0x7FFFu + ((u >> 16) & 1u)) >> 16;
  return (unsigned short)u;
}

// Coherence-bypassing 8 B accessors (relaxed agent-scope atomics ->
// global_{load,store}_dwordx2 sc0 sc1: through the non-coherent XCD L2 to the
// Infinity Cache; no buffer_wbl2/buffer_inv anywhere — r10/r11-proven).
__device__ inline void store8_agent(void* p, unsigned lo, unsigned hi) {
  const unsigned long long v = (unsigned long long)lo | ((unsigned long long)hi << 32);
  __hip_atomic_store((unsigned long long*)p, v, __ATOMIC_RELAXED,
                     __HIP_MEMORY_SCOPE_AGENT);
}
__device__ inline unsigned long long load8_agent(const void* p) {
  return __hip_atomic_load((const unsigned long long*)p, __ATOMIC_RELAXED,
                           __HIP_MEMORY_SCOPE_AGENT);
}

// ---------------- Fused persistent-chain path (batch == 512) ----------------
// 256 blocks = 32 groups x 8 members. Group g owns batch columns [16g,16g+16);
// member m owns A rows [64m,64m+64) (bf16 in LDS, MFMA-fragment order).
// Dt in global is PER-GROUP FRAGMENT-ORDERED (16 KB contiguous per group).
// Step path = r11's (best measured): barrier -> cooperative 16 KB stage to
// LDS (8 x 8 B coalesced sc0sc1 per thread, ONE latency exposure) -> stride-1
// ds_read_b128 B-frags -> 64 MFMAs -> recurrence -> 8 B fragment store.
// r13 vs r11: kSteps 7 -> 5 (see error analysis above).
// [r12's direct-to-register B-path regressed: +64 VGPRs staging arrays and
//  4x redundant IF traffic (per-wave duplicate loads) — reverted.]
__global__ __launch_bounds__(256) void cheb_fused(
    const float* __restrict__ x,    // [B, D]
    const float* __restrict__ t,    // [B]
    const float* __restrict__ mu,   // [D]
    const float* __restrict__ A,    // [D, D] fp32
    float* __restrict__ out,        // [B, D]
    unsigned short* __restrict__ Dt0,   // fragment-ordered ping (32 x 16 KB)
    unsigned short* __restrict__ Dt1,   // fragment-ordered pong
    unsigned* __restrict__ bars) {      // [32*kBarStride] zeroed counters
  const int group = blockIdx.x & (kGroupsC - 1);
  const int member = blockIdx.x >> 5;
  const int c0 = group * kCPG;
  const int i0 = member * kRowsB;
  const int tid = threadIdx.x;
  const int wave = tid >> 6;
  const int lane = tid & 63;
  const int quad = lane >> 4;
  const int lc = lane & 15;
  const int c = c0 + lc;                    // this thread's batch column
  const int ibase = i0 + wave * 16 + quad * 4;  // 4 consecutive k (=row) indices

  // Producer fragment address: slot = (k>>5)*64 + ((k>>3)&3)*16 + col,
  // elem = slot*8 + (k&7). Thread's k=ibase..ibase+3 -> one aligned 8 B piece.
  const size_t fragOff = (size_t)group * kFragElems +
      (size_t)(((ibase >> 5) * 64 + ((ibase >> 3) & 3) * 16 + lc) * 8 + (ibase & 7));

  // LDS: A slab (64 KB, fragment-ordered) + D staging (16 KB) -> 2 blocks/CU.
  __shared__ unsigned short As[kRowsB * kD];
  __shared__ unsigned short Ds[kFragElems];

  // --- per-column Chebyshev scalars (registers) ---
  const float tb = t[c];
  const float Bt = (kBetaMax - kBetaMin) / (2.0f * kTMax) * tb * tb + kBetaMin * tb;
  const float s_c = expm1f(Bt);
  const float eh = expf(0.5f * Bt);
  const float oscale = -eh * sqrtf(1.0f - expf(-Bt));
  const float theta = 0.5f * (kLamMin + kLamMax) + s_c;
  const float two_sig1 = 2.0f * theta / kDelta;
  const float c2base = 2.0f / kDelta;
  float rho_prev = kDelta / theta;          // 1/sigma1

  // --- state init + EARLY publish of D_1 (fragment-ordered 8 B store) ---
  float R[4], Dv[4], Y[4];
  {
    const float inv_theta = 1.0f / theta;
#pragma unroll
    for (int m = 0; m < 4; ++m) {
      const int i = ibase + m;
      const float b = eh * x[(size_t)c * kD + i] - mu[i];
      R[m] = b;
      Dv[m] = b * inv_theta;
      Y[m] = Dv[m];
    }
    store8_agent(Dt0 + fragOff,
                 (unsigned)bf16_rne(Dv[0]) | ((unsigned)bf16_rne(Dv[1]) << 16),
                 (unsigned)bf16_rne(Dv[2]) | ((unsigned)bf16_rne(Dv[3]) << 16));
  }

  // --- stage A slab fp32 -> bf16 (coalesced float4 reads) ---
  for (int idx = tid; idx < kRowsB * (kD / 4); idx += 256) {
    const int row = idx >> 7;
    const int col = (idx & 127) * 4;
    const float4 v = *(const float4*)(A + (size_t)(i0 + row) * kD + col);
    const int w = row >> 4, l = row & 15;
    const int kk = col >> 5, qd = (col >> 3) & 3, j = col & 7;
    uint2 wv;
    wv.x = (unsigned)bf16_rne(v.x) | ((unsigned)bf16_rne(v.y) << 16);
    wv.y = (unsigned)bf16_rne(v.z) | ((unsigned)bf16_rne(v.w) << 16);
    *(uint2*)&As[(w * 1024 + kk * 64 + qd * 16 + l) * 8 + j] = wv;
  }

  unsigned* ctr = bars + group * kBarStride;   // own 128 B line per group
  const unsigned short* groupIn0 = Dt0 + (size_t)group * kFragElems;
  const unsigned short* groupIn1 = Dt1 + (size_t)group * kFragElems;

  for (int k = 1; k <= kSteps; ++k) {
    // ---- 8-block group barrier (vmcnt drained by __syncthreads) ----
    __syncthreads();
    if (tid == 0) {
      __hip_atomic_fetch_add(ctr, 1u, __ATOMIC_RELAXED, __HIP_MEMORY_SCOPE_AGENT);
      const unsigned tgt = (unsigned)(kMembers * k);
      while (__hip_atomic_load(ctr, __ATOMIC_RELAXED, __HIP_MEMORY_SCOPE_AGENT) < tgt)
        __builtin_amdgcn_s_sleep(2);
    }
    __syncthreads();

    // ---- cooperative stage: group's 16 KB D-block -> LDS (coalesced) ----
    const unsigned short* gin = (k & 1) ? groupIn0 : groupIn1;
    unsigned long long stg[8];
#pragma unroll
    for (int i = 0; i < 8; ++i)
      stg[i] = load8_agent((const char*)gin + (size_t)i * 2048 + (size_t)tid * 8);
#pragma unroll
    for (int i = 0; i < 8; ++i)
      *(unsigned long long*)((char*)Ds + (size_t)i * 2048 + (size_t)tid * 8) = stg[i];
    __syncthreads();

    // ---- V-tile = A_slab x D (K = 512): B-frags from LDS, stride-1 b128 ----
    float4v acc = {0.f, 0.f, 0.f, 0.f};
    const unsigned short* afp = As + (size_t)(wave * 1024 + lane) * 8;
#pragma unroll
    for (int kk = 0; kk < kD / 32; ++kk) {
      const short8 af = *(const short8*)(afp + (size_t)kk * 64 * 8);
      const short8 bf = *(const short8*)(Ds + (size_t)(kk * 64 + lane) * 8);
      acc = __builtin_amdgcn_mfma_f32_16x16x32_bf16(af, bf, acc, 0, 0, 0);
    }

    // ---- Chebyshev recurrence (exact fp32 diagonal term s_c * D) ----
    const float rho_new = 1.0f / (two_sig1 - rho_prev);
    const float cc1 = rho_new * rho_prev;
    const float cc2 = rho_new * c2base;
#pragma unroll
    for (int m = 0; m < 4; ++m) {
      const float v = acc[m] + s_c * Dv[m];
      R[m] -= v;
      Dv[m] = fmaf(cc1, Dv[m], cc2 * R[m]);
      Y[m] += Dv[m];
    }
    rho_prev = rho_new;

    if (k < kSteps) {
      unsigned short* gout = ((k & 1) ? Dt1 : Dt0);
      store8_agent(gout + fragOff,
                   (unsigned)bf16_rne(Dv[0]) | ((unsigned)bf16_rne(Dv[1]) << 16),
                   (unsigned)bf16_rne(Dv[2]) | ((unsigned)bf16_rne(Dv[3]) << 16));
    } else {
      float4 o;
      o.x = oscale * Y[0];
      o.y = oscale * Y[1];
      o.z = oscale * Y[2];
      o.w = oscale * Y[3];
      *(float4*)(out + (size_t)c * kD + ibase) = o;
    }
  }
}

// ---------------- Fallback path (r6 kernel, any batch) ----------------
__device__ inline unsigned pack_bf16_rne2(float a, float b) {
  unsigned ua = __float_as_uint(a), ub = __float_as_uint(b);
  ua = (ua + 0x7FFFu + ((ua >> 16) & 1u)) >> 16;
  ub = (ub + 0x7FFFu + ((ub >> 16) & 1u)) >> 16;
  return ua | (ub << 16);
}

__global__ __launch_bounds__(256) void a_to_bf16(
    const float* __restrict__ A, unsigned* __restrict__ Abf) {
  const int i = blockIdx.x * 256 + threadIdx.x;
  const float4 f = ((const float4*)A)[i];
  uint2 u;
  u.x = pack_bf16_rne2(f.x, f.y);
  u.y = pack_bf16_rne2(f.z, f.w);
  ((uint2*)Abf)[i] = u;
}

namespace {
constexpr int fGroups = 8;
constexpr int fTPG = 128;
constexpr int fThreads = fGroups * fTPG;
constexpr int fRowsG = kD / fGroups;
constexpr int fG = 2;
constexpr int fDeg = 8;
constexpr int fRows = 8;
}

__global__ __launch_bounds__(fThreads) void vp_sde_cheb_fb(
    const float* __restrict__ x, const float* __restrict__ t,
    const float* __restrict__ mu, const uint2* __restrict__ Abf,
    float* __restrict__ out, int batch) {
  const int b0 = blockIdx.x * fG;
  const int tid = threadIdx.x;
  const int grp = tid >> 7;
  const int tl = tid & (fTPG - 1);
  const int d0 = 4 * tl;
  const int jbase = grp * fRowsG;

  __shared__ alignas(16) float d_sh[fG][kD];
  __shared__ alignas(16) float red_sh[fGroups - 1][fG][kD];

  float s[fG], two_sig1[fG], rho_prev[fG], oscale[fG];
  bool vld[fG];
  float4 y[fG], r[fG], dv[fG];
  const float two_over_delta = 2.0f / kDelta;

  uint2 buf0[fRows], buf1[fRows];
#pragma unroll
  for (int rr = 0; rr < fRows; ++rr)
    buf0[rr] = Abf[(size_t)(jbase + rr) * (kD / 4) + tl];

#pragma unroll
  for (int g = 0; g < fG; ++g) {
    const int b = b0 + g;
    vld[g] = (b < batch);
    const float tb = vld[g] ? t[b] : 1.0f;
    const float Bt = (kBetaMax - kBetaMin) / (2.0f * kTMax) * tb * tb + kBetaMin * tb;
    const float sg = expm1f(Bt);
    const float eh = expf(0.5f * Bt);
    s[g] = sg;
    oscale[g] = -eh * sqrtf(1.0f - expf(-Bt));
    const float theta = 0.5f * (kLamMin + kLamMax) + sg;
    const float sig1 = theta / kDelta;
    two_sig1[g] = 2.0f * sig1;
    rho_prev[g] = 1.0f / sig1;

    if (grp == 0) {
      float4 rv = {0.f, 0.f, 0.f, 0.f};
      if (vld[g]) {
        const float4 xv = *(const float4*)&x[(size_t)b * kD + d0];
        const float4 mu4 = *(const float4*)&mu[d0];
        rv.x = eh * xv.x - mu4.x;
        rv.y = eh * xv.y - mu4.y;
        rv.z = eh * xv.z - mu4.z;
        rv.w = eh * xv.w - mu4.w;
      }
      r[g] = rv;
      const float it = 1.0f / theta;
      dv[g].x = rv.x * it; dv[g].y = rv.y * it;
      dv[g].z = rv.z * it; dv[g].w = rv.w * it;
      y[g] = dv[g];
      *(float4*)&d_sh[g][d0] = dv[g];
    }
  }
  __syncthreads();

  for (int k = 1; k < fDeg; ++k) {
    float4 acc[fG];
#pragma unroll
    for (int g = 0; g < fG; ++g) acc[g] = {0.f, 0.f, 0.f, 0.f};

    auto stage = [&](uint2 (&cons)[fRows], uint2 (&ld)[fRows], int jc, int jl) {
#pragma unroll
      for (int rr = 0; rr < fRows; ++rr)
        ld[rr] = Abf[(size_t)(jbase + ((jl + rr) & (fRowsG - 1))) * (kD / 4) + tl];
      float4 pv[fG][fRows / 4];
#pragma unroll
      for (int g = 0; g < fG; ++g)
#pragma unroll
        for (int q = 0; q < fRows / 4; ++q)
          pv[g][q] = *(const float4*)&d_sh[g][jbase + jc + 4 * q];
#pragma unroll
      for (int q = 0; q < fRows / 4; ++q)
#pragma unroll
        for (int cc = 0; cc < 4; ++cc) {
          const uint2 u = cons[4 * q + cc];
          const float fa = __uint_as_float(u.x << 16);
          const float fb = __uint_as_float(u.x & 0xFFFF0000u);
          const float fc = __uint_as_float(u.y << 16);
          const float fd = __uint_as_float(u.y & 0xFFFF0000u);
#pragma unroll
          for (int g = 0; g < fG; ++g) {
            const float pj = (cc == 0) ? pv[g][q].x
                           : (cc == 1) ? pv[g][q].y
                           : (cc == 2) ? pv[g][q].z
                                       : pv[g][q].w;
            acc[g].x = fmaf(fa, pj, acc[g].x);
            acc[g].y = fmaf(fb, pj, acc[g].y);
            acc[g].z = fmaf(fc, pj, acc[g].z);
            acc[g].w = fmaf(fd, pj, acc[g].w);
          }
        }
    };

    int j = 0;
#pragma unroll 1
    for (int i = 0; i < fRowsG / (2 * fRows); ++i, j += 2 * fRows) {
      stage(buf0, buf1, j, j + fRows);
      stage(buf1, buf0, j + fRows, j + 2 * fRows);
    }

    if (grp != 0) {
#pragma unroll
      for (int g = 0; g < fG; ++g)
        *(float4*)&red_sh[grp - 1][g][d0] = acc[g];
    }
    __syncthreads();

    if (grp == 0) {
#pragma unroll
      for (int g = 0; g < fG; ++g) {
        float4 v = acc[g];
#pragma unroll
        for (int q = 0; q < fGroups - 1; ++q) {
          const float4 p = *(const float4*)&red_sh[q][g][d0];
          v.x += p.x; v.y += p.y; v.z += p.z; v.w += p.w;
        }
        v.x = fmaf(s[g], dv[g].x, v.x);
        v.y = fmaf(s[g], dv[g].y, v.y);
        v.z = fmaf(s[g], dv[g].z, v.z);
        v.w = fmaf(s[g], dv[g].w, v.w);
        r[g].x -= v.x; r[g].y -= v.y; r[g].z -= v.z; r[g].w -= v.w;
        const float rho = 1.0f / (two_sig1[g] - rho_prev[g]);
        const float c1 = rho * rho_prev[g];
        const float c2 = rho * two_over_delta;
        dv[g].x = fmaf(c1, dv[g].x, c2 * r[g].x);
        dv[g].y = fmaf(c1, dv[g].y, c2 * r[g].y);
        dv[g].z = fmaf(c1, dv[g].z, c2 * r[g].z);
        dv[g].w = fmaf(c1, dv[g].w, c2 * r[g].w);
        y[g].x += dv[g].x; y[g].y += dv[g].y;
        y[g].z += dv[g].z; y[g].w += dv[g].w;
        rho_prev[g] = rho;
        *(float4*)&d_sh[g][d0] = dv[g];
      }
    }
    __syncthreads();
  }

  if (grp == 0) {
#pragma unroll
    for (int g = 0; g < fG; ++g) {
      if (vld[g]) {
        float4 o;
        o.x = oscale[g] * y[g].x;
        o.y = oscale[g] * y[g].y;
        o.z = oscale[g] * y[g].z;
        o.w = oscale[g] * y[g].w;
        *(float4*)&out[(size_t)(b0 + g) * kD + d0] = o;
      }
    }
  }
}

extern "C" void kernel_launch(void* const* d_in, const int* in_sizes, int n_in,
                              void* d_out, int out_size, void* d_ws, size_t ws_size,
                              hipStream_t stream) {
  const float* x  = (const float*)d_in[0];   // [B, D] fp32
  const float* t  = (const float*)d_in[1];   // [B]    fp32
  const float* mu = (const float*)d_in[2];   // [D]    fp32
  const float* A  = (const float*)d_in[3];   // [D, D] fp32 SPD
  float* out = (float*)d_out;
  const int batch = in_sizes[1];

  char* ws = (char*)d_ws;
  const size_t barBytes = (size_t)kGroupsC * kBarStride * sizeof(unsigned);  // 4 KB
  const size_t need = 1024 * 1024 + barBytes;

  if (batch == kD && ws_size >= need) {
    unsigned short* Dt0 = (unsigned short*)(ws);                 // 512 KB
    unsigned short* Dt1 = (unsigned short*)(ws + 512 * 1024);    // 512 KB
    unsigned* bars = (unsigned*)(ws + 1024 * 1024);              // 4 KB

    hipMemsetAsync((void*)bars, 0, barBytes, stream);
    cheb_fused<<<kGroupsC * kMembers, 256, 0, stream>>>(
        x, t, mu, A, out, Dt0, Dt1, bars);
  } else {
    unsigned* Abf = (unsigned*)d_ws;
    a_to_bf16<<<(kD * kD / 4 + 255) / 256, 256, 0, stream>>>(A, Abf);
    const int blocks = (batch + fG - 1) / fG;
    vp_sde_cheb_fb<<<blocks, fThreads, 0, stream>>>(
        x, t, mu, (const uint2*)Abf, out, batch);
  }
}

// Round 14
// 71.644 us; speedup vs baseline: 1.1752x; 1.1042x over previous
//
#include <hip/hip_runtime.h>
#include <math.h>

namespace {
constexpr int kD = 512;
constexpr float kBetaMin = 0.1f;
constexpr float kBetaMax = 20.0f;
constexpr float kTMax = 1.0f;
// Spectrum of A = M M^T / D + I: lambda_min >= 1 (Wishart PSD),
// lambda_max ~ 4.96 (MP edge 4 + I + TW fluctuation). Containing bounds:
constexpr float kLamMin = 1.0f;
constexpr float kLamMax = 5.2f;
constexpr float kDelta = (kLamMax - kLamMin) * 0.5f;
// kSteps = matvec count (polynomial degree kSteps+1). Analytic worst-case
// truncation (over shift s, including the eh*rescale output scaling that
// vanishes where conditioning is worst): k=4 -> ~0.03-0.045 abs vs threshold
// 0.089. Measured absmax stayed at the bf16 floor (0.0156) for k=7,6,5 —
// truncation runs ~5x below the analytic bound.
constexpr int kSteps = 4;
constexpr int kGroupsC = 32;     // independent groups (16 batch-columns each)
constexpr int kMembers = 8;      // blocks per group (64 A-rows each)
constexpr int kCPG = 16;         // columns per group
constexpr int kRowsB = 64;       // A-rows per block (held in LDS)
constexpr int kBarStride = 32;   // unsigneds per counter -> 128 B line each
constexpr int kFragElems = kCPG * kD;   // 8192 bf16 = 16 KB per group D-block

typedef __attribute__((ext_vector_type(8))) short short8;   // 8 bf16
typedef __attribute__((ext_vector_type(4))) float float4v;  // 4 fp32 acc
}

__device__ inline unsigned short bf16_rne(float f) {
  unsigned u = __float_as_uint(f);
  u = (u + 0x7FFFu + ((u >> 16) & 1u)) >> 16;
  return (unsigned short)u;
}

__device__ inline unsigned pack_bf16_rne2(float a, float b) {
  unsigned ua = __float_as_uint(a), ub = __float_as_uint(b);
  ua = (ua + 0x7FFFu + ((ua >> 16) & 1u)) >> 16;
  ub = (ub + 0x7FFFu + ((ub >> 16) & 1u)) >> 16;
  return ua | (ub << 16);
}

// Coherence-bypassing 8 B accessors (relaxed agent-scope atomics ->
// global_{load,store}_dwordx2 sc0 sc1: through the non-coherent XCD L2 to the
// Infinity Cache; no buffer_wbl2/buffer_inv anywhere — r10/r11-proven).
__device__ inline void store8_agent(void* p, unsigned lo, unsigned hi) {
  const unsigned long long v = (unsigned long long)lo | ((unsigned long long)hi << 32);
  __hip_atomic_store((unsigned long long*)p, v, __ATOMIC_RELAXED,
                     __HIP_MEMORY_SCOPE_AGENT);
}
__device__ inline unsigned long long load8_agent(const void* p) {
  return __hip_atomic_load((const unsigned long long*)p, __ATOMIC_RELAXED,
                           __HIP_MEMORY_SCOPE_AGENT);
}

// Prologue (main path): A fp32 -> bf16 row-major into ws AND zero the barrier
// counters (folds the former hipMemsetAsync dispatch into this kernel).
// Kernel-boundary release makes both visible to the main kernel.
__global__ __launch_bounds__(256) void a_to_bf16_z(
    const float* __restrict__ A, unsigned* __restrict__ Abf,
    unsigned* __restrict__ bars) {
  const int i = blockIdx.x * 256 + threadIdx.x;
  const float4 f = ((const float4*)A)[i];
  uint2 u;
  u.x = pack_bf16_rne2(f.x, f.y);
  u.y = pack_bf16_rne2(f.z, f.w);
  ((uint2*)Abf)[i] = u;
  if (blockIdx.x == 0) {
#pragma unroll
    for (int q = 0; q < 4; ++q)
      bars[q * 256 + threadIdx.x] = 0u;   // 1024 uints = 32 groups x 32 stride
  }
}

// ---------------- Fused persistent-chain path (batch == 512) ----------------
// 256 blocks = 32 groups x 8 members. Group g owns batch columns [16g,16g+16);
// member m owns A rows [64m,64m+64) (bf16 in LDS, MFMA-fragment order).
// Dt in global is PER-GROUP FRAGMENT-ORDERED (16 KB contiguous per group).
// Step path (r11-proven): barrier -> cooperative 16 KB stage to LDS (8 x 8 B
// coalesced sc0sc1 per thread, ONE latency exposure) -> stride-1 ds_read_b128
// B-frags -> 64 MFMAs -> recurrence -> 8 B fragment store.
// r14 vs r13: (1) A arrives PRE-CONVERTED bf16 from the prologue -> block
// staging reads 64 KB (not 128 KB fp32) with zero conversion math on the
// critical path; (2) bars zeroed by prologue (memset dispatch removed);
// (3) kSteps 5 -> 4.
__global__ __launch_bounds__(256) void cheb_fused(
    const float* __restrict__ x,    // [B, D]
    const float* __restrict__ t,    // [B]
    const float* __restrict__ mu,   // [D]
    const unsigned short* __restrict__ Abf,  // [D, D] bf16 row-major
    float* __restrict__ out,        // [B, D]
    unsigned short* __restrict__ Dt0,   // fragment-ordered ping (32 x 16 KB)
    unsigned short* __restrict__ Dt1,   // fragment-ordered pong
    unsigned* __restrict__ bars) {      // [32*kBarStride] zeroed by prologue
  const int group = blockIdx.x & (kGroupsC - 1);
  const int member = blockIdx.x >> 5;
  const int c0 = group * kCPG;
  const int i0 = member * kRowsB;
  const int tid = threadIdx.x;
  const int wave = tid >> 6;
  const int lane = tid & 63;
  const int quad = lane >> 4;
  const int lc = lane & 15;
  const int c = c0 + lc;                    // this thread's batch column
  const int ibase = i0 + wave * 16 + quad * 4;  // 4 consecutive k (=row) indices

  // Producer fragment address: slot = (k>>5)*64 + ((k>>3)&3)*16 + col,
  // elem = slot*8 + (k&7). Thread's k=ibase..ibase+3 -> one aligned 8 B piece.
  const size_t fragOff = (size_t)group * kFragElems +
      (size_t)(((ibase >> 5) * 64 + ((ibase >> 3) & 3) * 16 + lc) * 8 + (ibase & 7));

  // LDS: A slab (64 KB, fragment-ordered) + D staging (16 KB) -> 2 blocks/CU.
  __shared__ unsigned short As[kRowsB * kD];
  __shared__ unsigned short Ds[kFragElems];

  // --- per-column Chebyshev scalars (registers) ---
  const float tb = t[c];
  const float Bt = (kBetaMax - kBetaMin) / (2.0f * kTMax) * tb * tb + kBetaMin * tb;
  const float s_c = expm1f(Bt);
  const float eh = expf(0.5f * Bt);
  const float oscale = -eh * sqrtf(1.0f - expf(-Bt));
  const float theta = 0.5f * (kLamMin + kLamMax) + s_c;
  const float two_sig1 = 2.0f * theta / kDelta;
  const float c2base = 2.0f / kDelta;
  float rho_prev = kDelta / theta;          // 1/sigma1

  // --- state init + EARLY publish of D_1 (fragment-ordered 8 B store) ---
  float R[4], Dv[4], Y[4];
  {
    const float inv_theta = 1.0f / theta;
#pragma unroll
    for (int m = 0; m < 4; ++m) {
      const int i = ibase + m;
      const float b = eh * x[(size_t)c * kD + i] - mu[i];
      R[m] = b;
      Dv[m] = b * inv_theta;
      Y[m] = Dv[m];
    }
    store8_agent(Dt0 + fragOff,
                 (unsigned)bf16_rne(Dv[0]) | ((unsigned)bf16_rne(Dv[1]) << 16),
                 (unsigned)bf16_rne(Dv[2]) | ((unsigned)bf16_rne(Dv[3]) << 16));
  }

  // --- stage A slab (already bf16): 16 B coalesced reads, fragment reorder ---
  for (int idx = tid; idx < kRowsB * (kD / 8); idx += 256) {
    const int row = idx >> 6;              // local row 0..63
    const int col = (idx & 63) * 8;        // j-run start (j=0)
    const uint4 v = *(const uint4*)(Abf + (size_t)(i0 + row) * kD + col);
    const int w = row >> 4, l = row & 15;
    const int kk = col >> 5, qd = (col >> 3) & 3;
    *(uint4*)&As[(w * 1024 + kk * 64 + qd * 16 + l) * 8] = v;
  }

  unsigned* ctr = bars + group * kBarStride;   // own 128 B line per group
  const unsigned short* groupIn0 = Dt0 + (size_t)group * kFragElems;
  const unsigned short* groupIn1 = Dt1 + (size_t)group * kFragElems;

  for (int k = 1; k <= kSteps; ++k) {
    // ---- 8-block group barrier (vmcnt drained by __syncthreads) ----
    __syncthreads();
    if (tid == 0) {
      __hip_atomic_fetch_add(ctr, 1u, __ATOMIC_RELAXED, __HIP_MEMORY_SCOPE_AGENT);
      const unsigned tgt = (unsigned)(kMembers * k);
      while (__hip_atomic_load(ctr, __ATOMIC_RELAXED, __HIP_MEMORY_SCOPE_AGENT) < tgt)
        __builtin_amdgcn_s_sleep(2);
    }
    __syncthreads();

    // ---- cooperative stage: group's 16 KB D-block -> LDS (coalesced) ----
    const unsigned short* gin = (k & 1) ? groupIn0 : groupIn1;
    unsigned long long stg[8];
#pragma unroll
    for (int i = 0; i < 8; ++i)
      stg[i] = load8_agent((const char*)gin + (size_t)i * 2048 + (size_t)tid * 8);
#pragma unroll
    for (int i = 0; i < 8; ++i)
      *(unsigned long long*)((char*)Ds + (size_t)i * 2048 + (size_t)tid * 8) = stg[i];
    __syncthreads();

    // ---- V-tile = A_slab x D (K = 512): B-frags from LDS, stride-1 b128 ----
    float4v acc = {0.f, 0.f, 0.f, 0.f};
    const unsigned short* afp = As + (size_t)(wave * 1024 + lane) * 8;
#pragma unroll
    for (int kk = 0; kk < kD / 32; ++kk) {
      const short8 af = *(const short8*)(afp + (size_t)kk * 64 * 8);
      const short8 bf = *(const short8*)(Ds + (size_t)(kk * 64 + lane) * 8);
      acc = __builtin_amdgcn_mfma_f32_16x16x32_bf16(af, bf, acc, 0, 0, 0);
    }

    // ---- Chebyshev recurrence (exact fp32 diagonal term s_c * D) ----
    const float rho_new = 1.0f / (two_sig1 - rho_prev);
    const float cc1 = rho_new * rho_prev;
    const float cc2 = rho_new * c2base;
#pragma unroll
    for (int m = 0; m < 4; ++m) {
      const float v = acc[m] + s_c * Dv[m];
      R[m] -= v;
      Dv[m] = fmaf(cc1, Dv[m], cc2 * R[m]);
      Y[m] += Dv[m];
    }
    rho_prev = rho_new;

    if (k < kSteps) {
      unsigned short* gout = ((k & 1) ? Dt1 : Dt0);
      store8_agent(gout + fragOff,
                   (unsigned)bf16_rne(Dv[0]) | ((unsigned)bf16_rne(Dv[1]) << 16),
                   (unsigned)bf16_rne(Dv[2]) | ((unsigned)bf16_rne(Dv[3]) << 16));
    } else {
      float4 o;
      o.x = oscale * Y[0];
      o.y = oscale * Y[1];
      o.z = oscale * Y[2];
      o.w = oscale * Y[3];
      *(float4*)(out + (size_t)c * kD + ibase) = o;
    }
  }
}

// ---------------- Fallback path (r6 kernel, any batch) ----------------
__global__ __launch_bounds__(256) void a_to_bf16(
    const float* __restrict__ A, unsigned* __restrict__ Abf) {
  const int i = blockIdx.x * 256 + threadIdx.x;
  const float4 f = ((const float4*)A)[i];
  uint2 u;
  u.x = pack_bf16_rne2(f.x, f.y);
  u.y = pack_bf16_rne2(f.z, f.w);
  ((uint2*)Abf)[i] = u;
}

namespace {
constexpr int fGroups = 8;
constexpr int fTPG = 128;
constexpr int fThreads = fGroups * fTPG;
constexpr int fRowsG = kD / fGroups;
constexpr int fG = 2;
constexpr int fDeg = 8;
constexpr int fRows = 8;
}

__global__ __launch_bounds__(fThreads) void vp_sde_cheb_fb(
    const float* __restrict__ x, const float* __restrict__ t,
    const float* __restrict__ mu, const uint2* __restrict__ Abf,
    float* __restrict__ out, int batch) {
  const int b0 = blockIdx.x * fG;
  const int tid = threadIdx.x;
  const int grp = tid >> 7;
  const int tl = tid & (fTPG - 1);
  const int d0 = 4 * tl;
  const int jbase = grp * fRowsG;

  __shared__ alignas(16) float d_sh[fG][kD];
  __shared__ alignas(16) float red_sh[fGroups - 1][fG][kD];

  float s[fG], two_sig1[fG], rho_prev[fG], oscale[fG];
  bool vld[fG];
  float4 y[fG], r[fG], dv[fG];
  const float two_over_delta = 2.0f / kDelta;

  uint2 buf0[fRows], buf1[fRows];
#pragma unroll
  for (int rr = 0; rr < fRows; ++rr)
    buf0[rr] = Abf[(size_t)(jbase + rr) * (kD / 4) + tl];

#pragma unroll
  for (int g = 0; g < fG; ++g) {
    const int b = b0 + g;
    vld[g] = (b < batch);
    const float tb = vld[g] ? t[b] : 1.0f;
    const float Bt = (kBetaMax - kBetaMin) / (2.0f * kTMax) * tb * tb + kBetaMin * tb;
    const float sg = expm1f(Bt);
    const float eh = expf(0.5f * Bt);
    s[g] = sg;
    oscale[g] = -eh * sqrtf(1.0f - expf(-Bt));
    const float theta = 0.5f * (kLamMin + kLamMax) + sg;
    const float sig1 = theta / kDelta;
    two_sig1[g] = 2.0f * sig1;
    rho_prev[g] = 1.0f / sig1;

    if (grp == 0) {
      float4 rv = {0.f, 0.f, 0.f, 0.f};
      if (vld[g]) {
        const float4 xv = *(const float4*)&x[(size_t)b * kD + d0];
        const float4 mu4 = *(const float4*)&mu[d0];
        rv.x = eh * xv.x - mu4.x;
        rv.y = eh * xv.y - mu4.y;
        rv.z = eh * xv.z - mu4.z;
        rv.w = eh * xv.w - mu4.w;
      }
      r[g] = rv;
      const float it = 1.0f / theta;
      dv[g].x = rv.x * it; dv[g].y = rv.y * it;
      dv[g].z = rv.z * it; dv[g].w = rv.w * it;
      y[g] = dv[g];
      *(float4*)&d_sh[g][d0] = dv[g];
    }
  }
  __syncthreads();

  for (int k = 1; k < fDeg; ++k) {
    float4 acc[fG];
#pragma unroll
    for (int g = 0; g < fG; ++g) acc[g] = {0.f, 0.f, 0.f, 0.f};

    auto stage = [&](uint2 (&cons)[fRows], uint2 (&ld)[fRows], int jc, int jl) {
#pragma unroll
      for (int rr = 0; rr < fRows; ++rr)
        ld[rr] = Abf[(size_t)(jbase + ((jl + rr) & (fRowsG - 1))) * (kD / 4) + tl];
      float4 pv[fG][fRows / 4];
#pragma unroll
      for (int g = 0; g < fG; ++g)
#pragma unroll
        for (int q = 0; q < fRows / 4; ++q)
          pv[g][q] = *(const float4*)&d_sh[g][jbase + jc + 4 * q];
#pragma unroll
      for (int q = 0; q < fRows / 4; ++q)
#pragma unroll
        for (int cc = 0; cc < 4; ++cc) {
          const uint2 u = cons[4 * q + cc];
          const float fa = __uint_as_float(u.x << 16);
          const float fb = __uint_as_float(u.x & 0xFFFF0000u);
          const float fc = __uint_as_float(u.y << 16);
          const float fd = __uint_as_float(u.y & 0xFFFF0000u);
#pragma unroll
          for (int g = 0; g < fG; ++g) {
            const float pj = (cc == 0) ? pv[g][q].x
                           : (cc == 1) ? pv[g][q].y
                           : (cc == 2) ? pv[g][q].z
                                       : pv[g][q].w;
            acc[g].x = fmaf(fa, pj, acc[g].x);
            acc[g].y = fmaf(fb, pj, acc[g].y);
            acc[g].z = fmaf(fc, pj, acc[g].z);
            acc[g].w = fmaf(fd, pj, acc[g].w);
          }
        }
    };

    int j = 0;
#pragma unroll 1
    for (int i = 0; i < fRowsG / (2 * fRows); ++i, j += 2 * fRows) {
      stage(buf0, buf1, j, j + fRows);
      stage(buf1, buf0, j + fRows, j + 2 * fRows);
    }

    if (grp != 0) {
#pragma unroll
      for (int g = 0; g < fG; ++g)
        *(float4*)&red_sh[grp - 1][g][d0] = acc[g];
    }
    __syncthreads();

    if (grp == 0) {
#pragma unroll
      for (int g = 0; g < fG; ++g) {
        float4 v = acc[g];
#pragma unroll
        for (int q = 0; q < fGroups - 1; ++q) {
          const float4 p = *(const float4*)&red_sh[q][g][d0];
          v.x += p.x; v.y += p.y; v.z += p.z; v.w += p.w;
        }
        v.x = fmaf(s[g], dv[g].x, v.x);
        v.y = fmaf(s[g], dv[g].y, v.y);
        v.z = fmaf(s[g], dv[g].z, v.z);
        v.w = fmaf(s[g], dv[g].w, v.w);
        r[g].x -= v.x; r[g].y -= v.y; r[g].z -= v.z; r[g].w -= v.w;
        const float rho = 1.0f / (two_sig1[g] - rho_prev[g]);
        const float c1 = rho * rho_prev[g];
        const float c2 = rho * two_over_delta;
        dv[g].x = fmaf(c1, dv[g].x, c2 * r[g].x);
        dv[g].y = fmaf(c1, dv[g].y, c2 * r[g].y);
        dv[g].z = fmaf(c1, dv[g].z, c2 * r[g].z);
        dv[g].w = fmaf(c1, dv[g].w, c2 * r[g].w);
        y[g].x += dv[g].x; y[g].y += dv[g].y;
        y[g].z += dv[g].z; y[g].w += dv[g].w;
        rho_prev[g] = rho;
        *(float4*)&d_sh[g][d0] = dv[g];
      }
    }
    __syncthreads();
  }

  if (grp == 0) {
#pragma unroll
    for (int g = 0; g < fG; ++g) {
      if (vld[g]) {
        float4 o;
        o.x = oscale[g] * y[g].x;
        o.y = oscale[g] * y[g].y;
        o.z = oscale[g] * y[g].z;
        o.w = oscale[g] * y[g].w;
        *(float4*)&out[(size_t)(b0 + g) * kD + d0] = o;
      }
    }
  }
}

extern "C" void kernel_launch(void* const* d_in, const int* in_sizes, int n_in,
                              void* d_out, int out_size, void* d_ws, size_t ws_size,
                              hipStream_t stream) {
  const float* x  = (const float*)d_in[0];   // [B, D] fp32
  const float* t  = (const float*)d_in[1];   // [B]    fp32
  const float* mu = (const float*)d_in[2];   // [D]    fp32
  const float* A  = (const float*)d_in[3];   // [D, D] fp32 SPD
  float* out = (float*)d_out;
  const int batch = in_sizes[1];

  char* ws = (char*)d_ws;
  const size_t barBytes = (size_t)kGroupsC * kBarStride * sizeof(unsigned);  // 4 KB
  const size_t need = 1536 * 1024 + barBytes;

  if (batch == kD && ws_size >= need) {
    unsigned short* Abf = (unsigned short*)(ws);                 // 512 KB bf16 A
    unsigned short* Dt0 = (unsigned short*)(ws + 512 * 1024);    // 512 KB
    unsigned short* Dt1 = (unsigned short*)(ws + 1024 * 1024);   // 512 KB
    unsigned* bars = (unsigned*)(ws + 1536 * 1024);              // 4 KB

    // Prologue: A -> bf16 + zero barrier counters (one dispatch, no memset).
    a_to_bf16_z<<<kD * kD / 4 / 256, 256, 0, stream>>>(A, (unsigned*)Abf, bars);
    cheb_fused<<<kGroupsC * kMembers, 256, 0, stream>>>(
        x, t, mu, Abf, out, Dt0, Dt1, bars);
  } else {
    unsigned* Abf = (unsigned*)d_ws;
    a_to_bf16<<<(kD * kD / 4 + 255) / 256, 256, 0, stream>>>(A, Abf);
    const int blocks = (batch + fG - 1) / fG;
    vp_sde_cheb_fb<<<blocks, fThreads, 0, stream>>>(
        x, t, mu, (const uint2*)Abf, out, batch);
  }
}